// Round 4
// baseline (295.894 us; speedup 1.0000x reference)
//
#include <hip/hip_runtime.h>
#include <hip/hip_fp16.h>

#define N_NODES 50000
#define E_EDGES 800000
#define SCAN_TILE 1024
#define SCAN_NBLK ((N_NODES + SCAN_TILE - 1) / SCAN_TILE)   // 49
#define NODES_PER_WAVE 8
#define NODE_WAVES ((N_NODES + NODES_PER_WAVE - 1) / NODES_PER_WAVE)   // 6250
#define NODE_BLOCKS ((NODE_WAVES + 3) / 4)                              // 1563

// ---------------------------------------------------------------------------
// Projection kernel: xq = q@Wq+bq, xk = k@Wk+bk, xv = v@Wv+bv  (N x 64 each)
// Outputs stored as fp16 to halve downstream gather traffic.
// ---------------------------------------------------------------------------
__global__ __launch_bounds__(256) void proj_kernel(
    const float* __restrict__ qin, const float* __restrict__ kin, const float* __restrict__ vin,
    const float* __restrict__ Wq, const float* __restrict__ bq,
    const float* __restrict__ Wk, const float* __restrict__ bk,
    const float* __restrict__ Wv, const float* __restrict__ bv,
    __half* __restrict__ xq, __half* __restrict__ xk, __half* __restrict__ xv)
{
    __shared__ float Ws[3 * 4096];
    const int tid = threadIdx.x;
    #pragma unroll
    for (int it = 0; it < 16; ++it) {
        const int idx = it * 256 + tid;
        Ws[idx]        = Wq[idx];
        Ws[4096 + idx] = Wk[idx];
        Ws[8192 + idx] = Wv[idx];
    }
    __syncthreads();

    const int cg = tid & 15;   // column group (4 cols)
    const int rg = tid >> 4;   // row group (4 rows)
    const int c0 = cg * 4;
    const int base = blockIdx.x * 64 + rg * 4;

    const float* ins[3]  = {qin, kin, vin};
    const float* bs[3]   = {bq, bk, bv};
    __half*      outs[3] = {xq, xk, xv};

    int rowi[4];
    #pragma unroll
    for (int rr = 0; rr < 4; ++rr)
        rowi[rr] = (base + rr < N_NODES) ? (base + rr) : (N_NODES - 1);

    #pragma unroll
    for (int m = 0; m < 3; ++m) {
        const float* in = ins[m];
        const float* Wm = &Ws[m * 4096];
        float4 acc[4];
        const float4 b4 = *reinterpret_cast<const float4*>(&bs[m][c0]);
        #pragma unroll
        for (int rr = 0; rr < 4; ++rr) acc[rr] = b4;

        for (int kk = 0; kk < 64; kk += 4) {
            float4 rv[4];
            #pragma unroll
            for (int rr = 0; rr < 4; ++rr)
                rv[rr] = *reinterpret_cast<const float4*>(&in[rowi[rr] * 64 + kk]);
            #pragma unroll
            for (int dk = 0; dk < 4; ++dk) {
                const float4 w4 = *reinterpret_cast<const float4*>(&Wm[(kk + dk) * 64 + c0]);
                #pragma unroll
                for (int rr = 0; rr < 4; ++rr) {
                    const float xs = reinterpret_cast<const float*>(&rv[rr])[dk];
                    acc[rr].x = fmaf(xs, w4.x, acc[rr].x);
                    acc[rr].y = fmaf(xs, w4.y, acc[rr].y);
                    acc[rr].z = fmaf(xs, w4.z, acc[rr].z);
                    acc[rr].w = fmaf(xs, w4.w, acc[rr].w);
                }
            }
        }
        #pragma unroll
        for (int rr = 0; rr < 4; ++rr) {
            if (base + rr < N_NODES) {
                union { __half2 h[2]; uint2 u; } pk;
                pk.h[0] = __floats2half2_rn(acc[rr].x, acc[rr].y);
                pk.h[1] = __floats2half2_rn(acc[rr].z, acc[rr].w);
                *reinterpret_cast<uint2*>(&outs[m][(size_t)(base + rr) * 64 + c0]) = pk.u;
            }
        }
    }
}

// ---------------------------------------------------------------------------
// CSR build step 1: per-src degree histogram
// ---------------------------------------------------------------------------
__global__ __launch_bounds__(256) void hist_kernel(
    const int* __restrict__ eidx, int* __restrict__ cnt)
{
    const int e = blockIdx.x * 256 + threadIdx.x;
    atomicAdd(&cnt[eidx[2 * e]], 1);
}

// ---------------------------------------------------------------------------
// Hierarchical scan, step A: per-1024-element block sums (49 blocks).
// ---------------------------------------------------------------------------
__global__ __launch_bounds__(256) void scan_sums(
    const int* __restrict__ cnt, int* __restrict__ bsum)
{
    const int tid  = threadIdx.x;
    const int base = blockIdx.x * SCAN_TILE + tid * 4;
    int s = 0;
    if (base + 3 < N_NODES) {
        const int4 t = *reinterpret_cast<const int4*>(&cnt[base]);
        s = t.x + t.y + t.z + t.w;
    } else {
        #pragma unroll
        for (int i = 0; i < 4; ++i)
            if (base + i < N_NODES) s += cnt[base + i];
    }
    #pragma unroll
    for (int d = 1; d < 64; d <<= 1) s += __shfl_xor(s, d);
    __shared__ int ws[4];
    if ((tid & 63) == 0) ws[tid >> 6] = s;
    __syncthreads();
    if (tid == 0) bsum[blockIdx.x] = ws[0] + ws[1] + ws[2] + ws[3];
}

// ---------------------------------------------------------------------------
// Hierarchical scan, step B: exclusive scan of the 49 block sums (one wave).
// ---------------------------------------------------------------------------
__global__ __launch_bounds__(64) void scan_bsum(int* __restrict__ bsum)
{
    const int lane = threadIdx.x;
    const int v = (lane < SCAN_NBLK) ? bsum[lane] : 0;
    int incl = v;
    #pragma unroll
    for (int d = 1; d < 64; d <<= 1) {
        const int t = __shfl_up(incl, d);
        if (lane >= d) incl += t;
    }
    if (lane < SCAN_NBLK) bsum[lane] = incl - v;   // exclusive prefix
}

// ---------------------------------------------------------------------------
// Hierarchical scan, step C: local exclusive scan + block offset.
// Writes off[] and re-purposes cnt[] (in-place) as the scatter cursor.
// ---------------------------------------------------------------------------
__global__ __launch_bounds__(256) void scan_final(
    int* __restrict__ cnt, const int* __restrict__ bsum, int* __restrict__ off)
{
    const int tid  = threadIdx.x;
    const int base = blockIdx.x * SCAN_TILE + tid * 4;

    int v0 = 0, v1 = 0, v2 = 0, v3 = 0;
    if (base + 3 < N_NODES) {
        const int4 t = *reinterpret_cast<const int4*>(&cnt[base]);
        v0 = t.x; v1 = t.y; v2 = t.z; v3 = t.w;
    } else {
        if (base + 0 < N_NODES) v0 = cnt[base + 0];
        if (base + 1 < N_NODES) v1 = cnt[base + 1];
        if (base + 2 < N_NODES) v2 = cnt[base + 2];
        if (base + 3 < N_NODES) v3 = cnt[base + 3];
    }
    const int s = v0 + v1 + v2 + v3;

    int incl = s;
    #pragma unroll
    for (int d = 1; d < 64; d <<= 1) {
        const int t = __shfl_up(incl, d);
        if ((tid & 63) >= d) incl += t;
    }
    __shared__ int wsum[4];
    const int wave = tid >> 6;
    if ((tid & 63) == 63) wsum[wave] = incl;
    __syncthreads();
    int woff = 0;
    #pragma unroll
    for (int w = 0; w < 3; ++w)
        if (w < wave) woff += wsum[w];

    int run = bsum[blockIdx.x] + woff + (incl - s);   // exclusive prefix
    if (base + 0 < N_NODES) { off[base + 0] = run; cnt[base + 0] = run; run += v0; }
    if (base + 1 < N_NODES) { off[base + 1] = run; cnt[base + 1] = run; run += v1; }
    if (base + 2 < N_NODES) { off[base + 2] = run; cnt[base + 2] = run; run += v2; }
    if (base + 3 < N_NODES) { off[base + 3] = run; cnt[base + 3] = run; run += v3; }

    if (blockIdx.x == 0 && tid == 0) off[N_NODES] = E_EDGES;
}

// ---------------------------------------------------------------------------
// CSR build step 3 (+ p_r precompute): scatter {p_r, dst} to CSR slot.
// ---------------------------------------------------------------------------
__global__ __launch_bounds__(256) void scatter_kernel(
    const int* __restrict__ eidx, const float* __restrict__ edges,
    const float* __restrict__ Wp, const float* __restrict__ bp,
    int* __restrict__ cursor, float2* __restrict__ epack)
{
    const int e = blockIdx.x * 256 + threadIdx.x;
    const int src = eidx[2 * e];
    const int dst = eidx[2 * e + 1];

    float pr = bp[0];
    #pragma unroll
    for (int q4 = 0; q4 < 4; ++q4) {
        const float4 ev = *reinterpret_cast<const float4*>(&edges[e * 16 + q4 * 4]);
        const float4 wv = *reinterpret_cast<const float4*>(&Wp[q4 * 4]);
        pr = fmaf(ev.x, wv.x, pr);
        pr = fmaf(ev.y, wv.y, pr);
        pr = fmaf(ev.z, wv.z, pr);
        pr = fmaf(ev.w, wv.w, pr);
    }

    const int pos = atomicAdd(&cursor[src], 1);
    epack[pos] = make_float2(pr, __int_as_float(dst));
}

// ---------------------------------------------------------------------------
// Node kernel (wave-per-node): the full wave processes one node at a time,
// 8 edges per chunk (octet o <-> edge j0+o; lane r keeps channels 8i+r).
// Octet-local shuffles for the MLP reduce + softmax; per-node cross-octet
// butterfly merges the 8 partial accumulators; coalesced 256B output store.
// ---------------------------------------------------------------------------
__global__ __launch_bounds__(256) void node_kernel(
    const int* __restrict__ off, const float2* __restrict__ epack,
    const float* __restrict__ W1, const float* __restrict__ b1,
    const float* __restrict__ W2, const float* __restrict__ b2,
    const __half* __restrict__ xq, const __half* __restrict__ xk, const __half* __restrict__ xv,
    float* __restrict__ out)
{
    const int tid  = threadIdx.x;
    const int lane = tid & 63;
    const int o    = lane >> 3;   // octet = edge slot within chunk
    const int r    = lane & 7;    // lane within octet = channel slot
    const int wave = tid >> 6;

    // ---- preload weights into registers (amortized over 8 nodes) ----
    float W1reg[8][8];   // rows c = 8*i + r, all 8 output cols
    #pragma unroll
    for (int i = 0; i < 8; ++i) {
        const float4 a = *reinterpret_cast<const float4*>(&W1[(8 * i + r) * 8]);
        const float4 b = *reinterpret_cast<const float4*>(&W1[(8 * i + r) * 8 + 4]);
        W1reg[i][0] = a.x; W1reg[i][1] = a.y; W1reg[i][2] = a.z; W1reg[i][3] = a.w;
        W1reg[i][4] = b.x; W1reg[i][5] = b.y; W1reg[i][6] = b.z; W1reg[i][7] = b.w;
    }
    float W2col[8];
    #pragma unroll
    for (int i = 0; i < 8; ++i) W2col[i] = W2[i * 8 + r];
    float b1reg[8];
    #pragma unroll
    for (int j = 0; j < 8; ++j) b1reg[j] = b1[j];
    const float b2r = b2[r];

    const int wid   = blockIdx.x * 4 + wave;
    const int nbeg  = wid * NODES_PER_WAVE;
    const int nend  = (nbeg + NODES_PER_WAVE < N_NODES) ? (nbeg + NODES_PER_WAVE) : N_NODES;

    for (int n = nbeg; n < nend; ++n) {
        const int beg = off[n];
        const int end = off[n + 1];

        float xqr[8];
        #pragma unroll
        for (int i = 0; i < 8; ++i)
            xqr[i] = __half2float(xq[(size_t)n * 64 + 8 * i + r]);

        float acc[8];
        #pragma unroll
        for (int i = 0; i < 8; ++i) acc[i] = 0.f;

        for (int j0 = beg; j0 < end; j0 += 8) {
            const int  je     = j0 + o;
            const bool active = (je < end);
            const int  jc     = active ? je : (end - 1);

            const float2 ep = epack[jc];
            const float p   = ep.x;
            const int   dst = __float_as_int(ep.y);
            const size_t drow = (size_t)dst * 64;

            // ---- h1 partials: relu(xk - xq + p) @ W1 ----
            float part[8];
            #pragma unroll
            for (int jj = 0; jj < 8; ++jj) part[jj] = 0.f;
            #pragma unroll
            for (int i = 0; i < 8; ++i) {
                const float a  = __half2float(xk[drow + 8 * i + r]) - xqr[i] + p;
                const float ar = fmaxf(a, 0.f);
                #pragma unroll
                for (int jj = 0; jj < 8; ++jj)
                    part[jj] = fmaf(ar, W1reg[i][jj], part[jj]);
            }
            #pragma unroll
            for (int jj = 0; jj < 8; ++jj) {
                part[jj] += __shfl_xor(part[jj], 1);
                part[jj] += __shfl_xor(part[jj], 2);
                part[jj] += __shfl_xor(part[jj], 4);
            }

            // ---- h2[r] = b2[r] + relu(h1) . W2[:, r] ----
            float h2 = b2r;
            #pragma unroll
            for (int jj = 0; jj < 8; ++jj) {
                const float h1 = fmaxf(part[jj] + b1reg[jj], 0.f);
                h2 = fmaf(h1, W2col[jj], h2);
            }

            // ---- softmax over the octet ----
            float mx = h2;
            mx = fmaxf(mx, __shfl_xor(mx, 1));
            mx = fmaxf(mx, __shfl_xor(mx, 2));
            mx = fmaxf(mx, __shfl_xor(mx, 4));
            const float ex = __expf(h2 - mx);
            float s = ex;
            s += __shfl_xor(s, 1);
            s += __shfl_xor(s, 2);
            s += __shfl_xor(s, 4);
            float sel = ex / s;
            sel = active ? sel : 0.f;

            // ---- accumulate msg = (xv + p) * sel ----
            #pragma unroll
            for (int i = 0; i < 8; ++i)
                acc[i] = fmaf(__half2float(xv[drow + 8 * i + r]) + p, sel, acc[i]);
        }

        // ---- cross-octet butterfly: sum the 8 per-octet partials ----
        #pragma unroll
        for (int i = 0; i < 8; ++i) {
            acc[i] += __shfl_xor(acc[i], 8);
            acc[i] += __shfl_xor(acc[i], 16);
            acc[i] += __shfl_xor(acc[i], 32);
        }

        // lane writes channel 8*o + r == lane; select acc[o] via cndmask chain
        float res = acc[0];
        #pragma unroll
        for (int i = 1; i < 8; ++i)
            if (o == i) res = acc[i];

        out[(size_t)n * 64 + lane] = res;
    }
}

extern "C" void kernel_launch(void* const* d_in, const int* in_sizes, int n_in,
                              void* d_out, int out_size, void* d_ws, size_t ws_size,
                              hipStream_t stream) {
    const float* q     = (const float*)d_in[0];
    const float* k     = (const float*)d_in[1];
    const float* v     = (const float*)d_in[2];
    const float* edges = (const float*)d_in[3];
    const int*   eidx  = (const int*)d_in[4];
    const float* Wq    = (const float*)d_in[5];
    const float* bq    = (const float*)d_in[6];
    const float* Wk    = (const float*)d_in[7];
    const float* bk    = (const float*)d_in[8];
    const float* Wv    = (const float*)d_in[9];
    const float* bv    = (const float*)d_in[10];
    const float* Wp    = (const float*)d_in[11];
    const float* bp    = (const float*)d_in[12];
    const float* W1    = (const float*)d_in[13];
    const float* b1    = (const float*)d_in[14];
    const float* W2    = (const float*)d_in[15];
    const float* b2    = (const float*)d_in[16];
    float* out = (float*)d_out;

    // workspace layout
    char* ws = (char*)d_ws;
    __half* xq = (__half*)ws;                        ws += (size_t)N_NODES * 64 * sizeof(__half);
    __half* xk = (__half*)ws;                        ws += (size_t)N_NODES * 64 * sizeof(__half);
    __half* xv = (__half*)ws;                        ws += (size_t)N_NODES * 64 * sizeof(__half);
    int* cnt  = (int*)ws;                            ws += (size_t)(N_NODES + 64) * sizeof(int);
    int* off  = (int*)ws;                            ws += (size_t)(N_NODES + 64) * sizeof(int);
    int* bsum = (int*)ws;                            ws += (size_t)64 * sizeof(int);
    float2* epack = (float2*)ws;                     ws += (size_t)E_EDGES * sizeof(float2);

    hipMemsetAsync(cnt, 0, (size_t)N_NODES * sizeof(int), stream);

    proj_kernel<<<dim3((N_NODES + 63) / 64), dim3(256), 0, stream>>>(
        q, k, v, Wq, bq, Wk, bk, Wv, bv, xq, xk, xv);

    hist_kernel<<<dim3(E_EDGES / 256), dim3(256), 0, stream>>>(eidx, cnt);

    scan_sums<<<dim3(SCAN_NBLK), dim3(256), 0, stream>>>(cnt, bsum);
    scan_bsum<<<dim3(1), dim3(64), 0, stream>>>(bsum);
    scan_final<<<dim3(SCAN_NBLK), dim3(256), 0, stream>>>(cnt, bsum, off);

    scatter_kernel<<<dim3(E_EDGES / 256), dim3(256), 0, stream>>>(
        eidx, edges, Wp, bp, cnt, epack);

    node_kernel<<<dim3(NODE_BLOCKS), dim3(256), 0, stream>>>(
        off, epack, W1, b1, W2, b2, xq, xk, xv, out);
}

// Round 5
// 217.499 us; speedup vs baseline: 1.3604x; 1.3604x over previous
//
#include <hip/hip_runtime.h>
#include <hip/hip_fp16.h>

#define N_NODES 50000
#define E_EDGES 800000
#define SCAN_TILE 1024
#define SCAN_NBLK ((N_NODES + SCAN_TILE - 1) / SCAN_TILE)   // 49

__device__ __forceinline__ float sgpr_f(float x) {
    return __uint_as_float(__builtin_amdgcn_readfirstlane(__float_as_uint(x)));
}

// ---------------------------------------------------------------------------
// Projection kernel: xq = q@Wq+bq, xk = k@Wk+bk, xv = v@Wv+bv  (N x 64 each)
// Outputs stored as fp16 to halve downstream gather traffic.
// ---------------------------------------------------------------------------
__global__ __launch_bounds__(256) void proj_kernel(
    const float* __restrict__ qin, const float* __restrict__ kin, const float* __restrict__ vin,
    const float* __restrict__ Wq, const float* __restrict__ bq,
    const float* __restrict__ Wk, const float* __restrict__ bk,
    const float* __restrict__ Wv, const float* __restrict__ bv,
    __half* __restrict__ xq, __half* __restrict__ xk, __half* __restrict__ xv)
{
    __shared__ float Ws[3 * 4096];
    const int tid = threadIdx.x;
    #pragma unroll
    for (int it = 0; it < 16; ++it) {
        const int idx = it * 256 + tid;
        Ws[idx]        = Wq[idx];
        Ws[4096 + idx] = Wk[idx];
        Ws[8192 + idx] = Wv[idx];
    }
    __syncthreads();

    const int cg = tid & 15;   // column group (4 cols)
    const int rg = tid >> 4;   // row group (4 rows)
    const int c0 = cg * 4;
    const int base = blockIdx.x * 64 + rg * 4;

    const float* ins[3]  = {qin, kin, vin};
    const float* bs[3]   = {bq, bk, bv};
    __half*      outs[3] = {xq, xk, xv};

    int rowi[4];
    #pragma unroll
    for (int rr = 0; rr < 4; ++rr)
        rowi[rr] = (base + rr < N_NODES) ? (base + rr) : (N_NODES - 1);

    #pragma unroll
    for (int m = 0; m < 3; ++m) {
        const float* in = ins[m];
        const float* Wm = &Ws[m * 4096];
        float4 acc[4];
        const float4 b4 = *reinterpret_cast<const float4*>(&bs[m][c0]);
        #pragma unroll
        for (int rr = 0; rr < 4; ++rr) acc[rr] = b4;

        for (int kk = 0; kk < 64; kk += 4) {
            float4 rv[4];
            #pragma unroll
            for (int rr = 0; rr < 4; ++rr)
                rv[rr] = *reinterpret_cast<const float4*>(&in[rowi[rr] * 64 + kk]);
            #pragma unroll
            for (int dk = 0; dk < 4; ++dk) {
                const float4 w4 = *reinterpret_cast<const float4*>(&Wm[(kk + dk) * 64 + c0]);
                #pragma unroll
                for (int rr = 0; rr < 4; ++rr) {
                    const float xs = reinterpret_cast<const float*>(&rv[rr])[dk];
                    acc[rr].x = fmaf(xs, w4.x, acc[rr].x);
                    acc[rr].y = fmaf(xs, w4.y, acc[rr].y);
                    acc[rr].z = fmaf(xs, w4.z, acc[rr].z);
                    acc[rr].w = fmaf(xs, w4.w, acc[rr].w);
                }
            }
        }
        #pragma unroll
        for (int rr = 0; rr < 4; ++rr) {
            if (base + rr < N_NODES) {
                union { __half2 h[2]; uint2 u; } pk;
                pk.h[0] = __floats2half2_rn(acc[rr].x, acc[rr].y);
                pk.h[1] = __floats2half2_rn(acc[rr].z, acc[rr].w);
                *reinterpret_cast<uint2*>(&outs[m][(size_t)(base + rr) * 64 + c0]) = pk.u;
            }
        }
    }
}

// ---------------------------------------------------------------------------
// CSR build step 1: per-src degree histogram
// ---------------------------------------------------------------------------
__global__ __launch_bounds__(256) void hist_kernel(
    const int* __restrict__ eidx, int* __restrict__ cnt)
{
    const int e = blockIdx.x * 256 + threadIdx.x;
    atomicAdd(&cnt[eidx[2 * e]], 1);
}

// ---------------------------------------------------------------------------
// Hierarchical scan, step A: per-1024-element block sums (49 blocks).
// ---------------------------------------------------------------------------
__global__ __launch_bounds__(256) void scan_sums(
    const int* __restrict__ cnt, int* __restrict__ bsum)
{
    const int tid  = threadIdx.x;
    const int base = blockIdx.x * SCAN_TILE + tid * 4;
    int s = 0;
    if (base + 3 < N_NODES) {
        const int4 t = *reinterpret_cast<const int4*>(&cnt[base]);
        s = t.x + t.y + t.z + t.w;
    } else {
        #pragma unroll
        for (int i = 0; i < 4; ++i)
            if (base + i < N_NODES) s += cnt[base + i];
    }
    #pragma unroll
    for (int d = 1; d < 64; d <<= 1) s += __shfl_xor(s, d);
    __shared__ int ws[4];
    if ((tid & 63) == 0) ws[tid >> 6] = s;
    __syncthreads();
    if (tid == 0) bsum[blockIdx.x] = ws[0] + ws[1] + ws[2] + ws[3];
}

// ---------------------------------------------------------------------------
// Hierarchical scan, step B: exclusive scan of the 49 block sums (one wave).
// ---------------------------------------------------------------------------
__global__ __launch_bounds__(64) void scan_bsum(int* __restrict__ bsum)
{
    const int lane = threadIdx.x;
    const int v = (lane < SCAN_NBLK) ? bsum[lane] : 0;
    int incl = v;
    #pragma unroll
    for (int d = 1; d < 64; d <<= 1) {
        const int t = __shfl_up(incl, d);
        if (lane >= d) incl += t;
    }
    if (lane < SCAN_NBLK) bsum[lane] = incl - v;   // exclusive prefix
}

// ---------------------------------------------------------------------------
// Hierarchical scan, step C: local exclusive scan + block offset.
// Writes off[] and re-purposes cnt[] (in-place) as the scatter cursor.
// ---------------------------------------------------------------------------
__global__ __launch_bounds__(256) void scan_final(
    int* __restrict__ cnt, const int* __restrict__ bsum, int* __restrict__ off)
{
    const int tid  = threadIdx.x;
    const int base = blockIdx.x * SCAN_TILE + tid * 4;

    int v0 = 0, v1 = 0, v2 = 0, v3 = 0;
    if (base + 3 < N_NODES) {
        const int4 t = *reinterpret_cast<const int4*>(&cnt[base]);
        v0 = t.x; v1 = t.y; v2 = t.z; v3 = t.w;
    } else {
        if (base + 0 < N_NODES) v0 = cnt[base + 0];
        if (base + 1 < N_NODES) v1 = cnt[base + 1];
        if (base + 2 < N_NODES) v2 = cnt[base + 2];
        if (base + 3 < N_NODES) v3 = cnt[base + 3];
    }
    const int s = v0 + v1 + v2 + v3;

    int incl = s;
    #pragma unroll
    for (int d = 1; d < 64; d <<= 1) {
        const int t = __shfl_up(incl, d);
        if ((tid & 63) >= d) incl += t;
    }
    __shared__ int wsum[4];
    const int wave = tid >> 6;
    if ((tid & 63) == 63) wsum[wave] = incl;
    __syncthreads();
    int woff = 0;
    #pragma unroll
    for (int w = 0; w < 3; ++w)
        if (w < wave) woff += wsum[w];

    int run = bsum[blockIdx.x] + woff + (incl - s);   // exclusive prefix
    if (base + 0 < N_NODES) { off[base + 0] = run; cnt[base + 0] = run; run += v0; }
    if (base + 1 < N_NODES) { off[base + 1] = run; cnt[base + 1] = run; run += v1; }
    if (base + 2 < N_NODES) { off[base + 2] = run; cnt[base + 2] = run; run += v2; }
    if (base + 3 < N_NODES) { off[base + 3] = run; cnt[base + 3] = run; run += v3; }

    if (blockIdx.x == 0 && tid == 0) off[N_NODES] = E_EDGES;
}

// ---------------------------------------------------------------------------
// CSR build step 3 (+ p_r precompute): scatter {p_r, dst} to CSR slot.
// ---------------------------------------------------------------------------
__global__ __launch_bounds__(256) void scatter_kernel(
    const int* __restrict__ eidx, const float* __restrict__ edges,
    const float* __restrict__ Wp, const float* __restrict__ bp,
    int* __restrict__ cursor, float2* __restrict__ epack)
{
    const int e = blockIdx.x * 256 + threadIdx.x;
    const int src = eidx[2 * e];
    const int dst = eidx[2 * e + 1];

    float pr = bp[0];
    #pragma unroll
    for (int q4 = 0; q4 < 4; ++q4) {
        const float4 ev = *reinterpret_cast<const float4*>(&edges[e * 16 + q4 * 4]);
        const float4 wv = *reinterpret_cast<const float4*>(&Wp[q4 * 4]);
        pr = fmaf(ev.x, wv.x, pr);
        pr = fmaf(ev.y, wv.y, pr);
        pr = fmaf(ev.z, wv.z, pr);
        pr = fmaf(ev.w, wv.w, pr);
    }

    const int pos = atomicAdd(&cursor[src], 1);
    epack[pos] = make_float2(pr, __int_as_float(dst));
}

// ---------------------------------------------------------------------------
// Node kernel (octet-per-node, contiguous channel blocks):
// lane r owns channels c in [8r, 8r+8) -> one dwordx4 fp16 load per node-row.
// Octet-local shuffles reduce the 64-ch W1 partials; every lane then computes
// all 8 logits + a fully local softmax (weight for channel 8r+j is w[j]).
// ---------------------------------------------------------------------------
__global__ __launch_bounds__(256) void node_kernel(
    const int* __restrict__ off, const float2* __restrict__ epack,
    const float* __restrict__ W1, const float* __restrict__ b1,
    const float* __restrict__ W2, const float* __restrict__ b2,
    const __half* __restrict__ xq, const __half* __restrict__ xk, const __half* __restrict__ xv,
    float* __restrict__ out)
{
    const int tid  = threadIdx.x;
    const int lane = tid & 63;
    const int o    = lane >> 3;   // octet within wave (node slot)
    const int r    = lane & 7;    // channel block within octet
    const int wave = tid >> 6;

    // ---- lane-dependent W1 slice: rows 8r..8r+7 (64 consecutive floats) ----
    float W1reg[8][8];
    #pragma unroll
    for (int i = 0; i < 8; ++i) {
        const float4 a = *reinterpret_cast<const float4*>(&W1[(8 * r + i) * 8]);
        const float4 b = *reinterpret_cast<const float4*>(&W1[(8 * r + i) * 8 + 4]);
        W1reg[i][0] = a.x; W1reg[i][1] = a.y; W1reg[i][2] = a.z; W1reg[i][3] = a.w;
        W1reg[i][4] = b.x; W1reg[i][5] = b.y; W1reg[i][6] = b.z; W1reg[i][7] = b.w;
    }
    // ---- uniform weights -> SGPRs via readfirstlane ----
    float W2u[8][8];
    #pragma unroll
    for (int jj = 0; jj < 8; ++jj)
        #pragma unroll
        for (int j = 0; j < 8; ++j)
            W2u[jj][j] = sgpr_f(W2[jj * 8 + j]);
    float b1u[8], b2u[8];
    #pragma unroll
    for (int j = 0; j < 8; ++j) { b1u[j] = sgpr_f(b1[j]); b2u[j] = sgpr_f(b2[j]); }

    const int node = (blockIdx.x * 4 + wave) * 8 + o;
    if (node >= N_NODES) return;   // octet-local shuffles only; safe exit

    const int beg = off[node];
    const int end = off[node + 1];

    // ---- xq row slice: one 16B load of 8 halves ----
    float xqr[8];
    {
        union { uint4 u; __half2 h[4]; } q4;
        q4.u = *reinterpret_cast<const uint4*>(&xq[(size_t)node * 64 + 8 * r]);
        #pragma unroll
        for (int i = 0; i < 4; ++i) {
            const float2 f = __half22float2(q4.h[i]);
            xqr[2 * i]     = f.x;
            xqr[2 * i + 1] = f.y;
        }
    }

    float acc[8];
    #pragma unroll
    for (int j = 0; j < 8; ++j) acc[j] = 0.f;

    float2 ep = (beg < end) ? epack[beg] : make_float2(0.f, 0.f);

    for (int j = beg; j < end; ++j) {
        const float p   = ep.x;
        const int   dst = __float_as_int(ep.y);
        const size_t dbase = (size_t)dst * 64 + 8 * r;

        // issue row loads for this edge
        union { uint4 u; __half2 h[4]; } k4, v4;
        k4.u = *reinterpret_cast<const uint4*>(&xk[dbase]);
        v4.u = *reinterpret_cast<const uint4*>(&xv[dbase]);

        // prefetch next edge record (independent)
        if (j + 1 < end) ep = epack[j + 1];

        float kf[8], vf[8];
        #pragma unroll
        for (int i = 0; i < 4; ++i) {
            const float2 fk = __half22float2(k4.h[i]);
            const float2 fv = __half22float2(v4.h[i]);
            kf[2 * i] = fk.x; kf[2 * i + 1] = fk.y;
            vf[2 * i] = fv.x; vf[2 * i + 1] = fv.y;
        }

        // ---- h1 partials over this lane's 8 channels ----
        float part[8];
        #pragma unroll
        for (int jj = 0; jj < 8; ++jj) part[jj] = 0.f;
        #pragma unroll
        for (int i = 0; i < 8; ++i) {
            const float ar = fmaxf(kf[i] - xqr[i] + p, 0.f);
            #pragma unroll
            for (int jj = 0; jj < 8; ++jj)
                part[jj] = fmaf(ar, W1reg[i][jj], part[jj]);
        }
        // octet reduce -> every lane holds full h1
        #pragma unroll
        for (int jj = 0; jj < 8; ++jj) {
            part[jj] += __shfl_xor(part[jj], 1);
            part[jj] += __shfl_xor(part[jj], 2);
            part[jj] += __shfl_xor(part[jj], 4);
        }

        // ---- all 8 logits locally ----
        float h2[8];
        #pragma unroll
        for (int j2 = 0; j2 < 8; ++j2) h2[j2] = b2u[j2];
        #pragma unroll
        for (int jj = 0; jj < 8; ++jj) {
            const float h1 = fmaxf(part[jj] + b1u[jj], 0.f);
            #pragma unroll
            for (int j2 = 0; j2 < 8; ++j2)
                h2[j2] = fmaf(h1, W2u[jj][j2], h2[j2]);
        }

        // ---- lane-local softmax over the 8 logits ----
        float mx = h2[0];
        #pragma unroll
        for (int j2 = 1; j2 < 8; ++j2) mx = fmaxf(mx, h2[j2]);
        float ex[8], s = 0.f;
        #pragma unroll
        for (int j2 = 0; j2 < 8; ++j2) { ex[j2] = __expf(h2[j2] - mx); s += ex[j2]; }
        const float inv = 1.f / s;

        // ---- accumulate msg: channel 8r+j2 gets weight w[j2] ----
        #pragma unroll
        for (int j2 = 0; j2 < 8; ++j2)
            acc[j2] = fmaf(vf[j2] + p, ex[j2] * inv, acc[j2]);
    }

    // ---- coalesced output: lane r writes channels 8r..8r+7 ----
    float4 o0 = make_float4(acc[0], acc[1], acc[2], acc[3]);
    float4 o1 = make_float4(acc[4], acc[5], acc[6], acc[7]);
    float* orow = &out[(size_t)node * 64 + 8 * r];
    *reinterpret_cast<float4*>(orow)     = o0;
    *reinterpret_cast<float4*>(orow + 4) = o1;
}

extern "C" void kernel_launch(void* const* d_in, const int* in_sizes, int n_in,
                              void* d_out, int out_size, void* d_ws, size_t ws_size,
                              hipStream_t stream) {
    const float* q     = (const float*)d_in[0];
    const float* k     = (const float*)d_in[1];
    const float* v     = (const float*)d_in[2];
    const float* edges = (const float*)d_in[3];
    const int*   eidx  = (const int*)d_in[4];
    const float* Wq    = (const float*)d_in[5];
    const float* bq    = (const float*)d_in[6];
    const float* Wk    = (const float*)d_in[7];
    const float* bk    = (const float*)d_in[8];
    const float* Wv    = (const float*)d_in[9];
    const float* bv    = (const float*)d_in[10];
    const float* Wp    = (const float*)d_in[11];
    const float* bp    = (const float*)d_in[12];
    const float* W1    = (const float*)d_in[13];
    const float* b1    = (const float*)d_in[14];
    const float* W2    = (const float*)d_in[15];
    const float* b2    = (const float*)d_in[16];
    float* out = (float*)d_out;

    // workspace layout
    char* ws = (char*)d_ws;
    __half* xq = (__half*)ws;                        ws += (size_t)N_NODES * 64 * sizeof(__half);
    __half* xk = (__half*)ws;                        ws += (size_t)N_NODES * 64 * sizeof(__half);
    __half* xv = (__half*)ws;                        ws += (size_t)N_NODES * 64 * sizeof(__half);
    int* cnt  = (int*)ws;                            ws += (size_t)(N_NODES + 64) * sizeof(int);
    int* off  = (int*)ws;                            ws += (size_t)(N_NODES + 64) * sizeof(int);
    int* bsum = (int*)ws;                            ws += (size_t)64 * sizeof(int);
    float2* epack = (float2*)ws;                     ws += (size_t)E_EDGES * sizeof(float2);

    hipMemsetAsync(cnt, 0, (size_t)N_NODES * sizeof(int), stream);

    proj_kernel<<<dim3((N_NODES + 63) / 64), dim3(256), 0, stream>>>(
        q, k, v, Wq, bq, Wk, bk, Wv, bv, xq, xk, xv);

    hist_kernel<<<dim3(E_EDGES / 256), dim3(256), 0, stream>>>(eidx, cnt);

    scan_sums<<<dim3(SCAN_NBLK), dim3(256), 0, stream>>>(cnt, bsum);
    scan_bsum<<<dim3(1), dim3(64), 0, stream>>>(bsum);
    scan_final<<<dim3(SCAN_NBLK), dim3(256), 0, stream>>>(cnt, bsum, off);

    scatter_kernel<<<dim3(E_EDGES / 256), dim3(256), 0, stream>>>(
        eidx, edges, Wp, bp, cnt, epack);

    node_kernel<<<dim3((N_NODES + 31) / 32), dim3(256), 0, stream>>>(
        off, epack, W1, b1, W2, b2, xq, xk, xv, out);
}

// Round 6
// 191.072 us; speedup vs baseline: 1.5486x; 1.1383x over previous
//
#include <hip/hip_runtime.h>
#include <hip/hip_fp16.h>

#define N_NODES 50000
#define E_EDGES 800000
#define SCAN_TILE 1024
#define SCAN_NBLK ((N_NODES + SCAN_TILE - 1) / SCAN_TILE)   // 49
#define EW_EPT 8    // edges per thread in edge_weights

__device__ __forceinline__ float sgpr_f(float x) {
    return __uint_as_float(__builtin_amdgcn_readfirstlane(__float_as_uint(x)));
}

// ---------------------------------------------------------------------------
// Projection kernel: xq = q@Wq+bq, xk = k@Wk+bk, xv = v@Wv+bv  (N x 64 each)
// Outputs stored as fp16 to halve downstream gather traffic.
// ---------------------------------------------------------------------------
__global__ __launch_bounds__(256) void proj_kernel(
    const float* __restrict__ qin, const float* __restrict__ kin, const float* __restrict__ vin,
    const float* __restrict__ Wq, const float* __restrict__ bq,
    const float* __restrict__ Wk, const float* __restrict__ bk,
    const float* __restrict__ Wv, const float* __restrict__ bv,
    __half* __restrict__ xq, __half* __restrict__ xk, __half* __restrict__ xv)
{
    __shared__ float Ws[3 * 4096];
    const int tid = threadIdx.x;
    #pragma unroll
    for (int it = 0; it < 16; ++it) {
        const int idx = it * 256 + tid;
        Ws[idx]        = Wq[idx];
        Ws[4096 + idx] = Wk[idx];
        Ws[8192 + idx] = Wv[idx];
    }
    __syncthreads();

    const int cg = tid & 15;
    const int rg = tid >> 4;
    const int c0 = cg * 4;
    const int base = blockIdx.x * 64 + rg * 4;

    const float* ins[3]  = {qin, kin, vin};
    const float* bs[3]   = {bq, bk, bv};
    __half*      outs[3] = {xq, xk, xv};

    int rowi[4];
    #pragma unroll
    for (int rr = 0; rr < 4; ++rr)
        rowi[rr] = (base + rr < N_NODES) ? (base + rr) : (N_NODES - 1);

    #pragma unroll
    for (int m = 0; m < 3; ++m) {
        const float* in = ins[m];
        const float* Wm = &Ws[m * 4096];
        float4 acc[4];
        const float4 b4 = *reinterpret_cast<const float4*>(&bs[m][c0]);
        #pragma unroll
        for (int rr = 0; rr < 4; ++rr) acc[rr] = b4;

        for (int kk = 0; kk < 64; kk += 4) {
            float4 rv[4];
            #pragma unroll
            for (int rr = 0; rr < 4; ++rr)
                rv[rr] = *reinterpret_cast<const float4*>(&in[rowi[rr] * 64 + kk]);
            #pragma unroll
            for (int dk = 0; dk < 4; ++dk) {
                const float4 w4 = *reinterpret_cast<const float4*>(&Wm[(kk + dk) * 64 + c0]);
                #pragma unroll
                for (int rr = 0; rr < 4; ++rr) {
                    const float xs = reinterpret_cast<const float*>(&rv[rr])[dk];
                    acc[rr].x = fmaf(xs, w4.x, acc[rr].x);
                    acc[rr].y = fmaf(xs, w4.y, acc[rr].y);
                    acc[rr].z = fmaf(xs, w4.z, acc[rr].z);
                    acc[rr].w = fmaf(xs, w4.w, acc[rr].w);
                }
            }
        }
        #pragma unroll
        for (int rr = 0; rr < 4; ++rr) {
            if (base + rr < N_NODES) {
                union { __half2 h[2]; uint2 u; } pk;
                pk.h[0] = __floats2half2_rn(acc[rr].x, acc[rr].y);
                pk.h[1] = __floats2half2_rn(acc[rr].z, acc[rr].w);
                *reinterpret_cast<uint2*>(&outs[m][(size_t)(base + rr) * 64 + c0]) = pk.u;
            }
        }
    }
}

// ---------------------------------------------------------------------------
// Edge-weights kernel (balanced, edge-parallel, original edge order):
// octet (8 lanes) per edge, 8 edges per wave per iteration, EW_EPT iterations.
// Lane r: channels 8r..8r+7 of the edge's node rows (one dwordx4 fp16 load).
// Distributed logits (lane r computes only h2[r]); octet softmax via shuffles.
// Writes: 8 fp16 weights per edge (coalesced 2B/lane) + p (f32, lane 0).
// Also builds the degree histogram (lane 1 atomic).
// ---------------------------------------------------------------------------
__global__ __launch_bounds__(256) void edge_weights(
    const int* __restrict__ eidx, const float* __restrict__ edges,
    const float* __restrict__ Wp, const float* __restrict__ bp,
    const float* __restrict__ W1, const float* __restrict__ b1,
    const float* __restrict__ W2, const float* __restrict__ b2,
    const __half* __restrict__ xq, const __half* __restrict__ xk,
    ushort* __restrict__ wout, float* __restrict__ pf, int* __restrict__ cnt)
{
    const int tid  = threadIdx.x;
    const int lane = tid & 63;
    const int o    = lane >> 3;
    const int r    = lane & 7;
    const int wave = tid >> 6;

    // W1 slice for this lane's channels 8r..8r+7 (all 8 output cols)
    float W1reg[8][8];
    #pragma unroll
    for (int i = 0; i < 8; ++i) {
        const float4 a = *reinterpret_cast<const float4*>(&W1[(8 * r + i) * 8]);
        const float4 b = *reinterpret_cast<const float4*>(&W1[(8 * r + i) * 8 + 4]);
        W1reg[i][0] = a.x; W1reg[i][1] = a.y; W1reg[i][2] = a.z; W1reg[i][3] = a.w;
        W1reg[i][4] = b.x; W1reg[i][5] = b.y; W1reg[i][6] = b.z; W1reg[i][7] = b.w;
    }
    // W2 column r (per-lane) for the distributed logit
    float W2col[8];
    #pragma unroll
    for (int jj = 0; jj < 8; ++jj) W2col[jj] = W2[jj * 8 + r];
    // uniform biases -> SGPRs
    float b1u[8];
    #pragma unroll
    for (int j = 0; j < 8; ++j) b1u[j] = sgpr_f(b1[j]);
    const float b2r = b2[r];
    const float wpA = Wp[2 * r], wpB = Wp[2 * r + 1];
    const float bp0 = sgpr_f(bp[0]);

    const int wb = (blockIdx.x * 4 + wave) * (8 * EW_EPT);

    #pragma unroll
    for (int t = 0; t < EW_EPT; ++t) {
        const int e = wb + t * 8 + o;

        const int2 sd = *reinterpret_cast<const int2*>(&eidx[2 * e]);
        const float2 e2 = *reinterpret_cast<const float2*>(&edges[(size_t)e * 16 + 2 * r]);

        union { uint4 u; __half2 h[4]; } q4, k4;
        q4.u = *reinterpret_cast<const uint4*>(&xq[(size_t)sd.x * 64 + 8 * r]);
        k4.u = *reinterpret_cast<const uint4*>(&xk[(size_t)sd.y * 64 + 8 * r]);

        // p = edges[e].Wp + bp  (16-dot over octet)
        float p = fmaf(e2.x, wpA, e2.y * wpB);
        p += __shfl_xor(p, 1);
        p += __shfl_xor(p, 2);
        p += __shfl_xor(p, 4);
        p += bp0;

        float qf[8], kf[8];
        #pragma unroll
        for (int i = 0; i < 4; ++i) {
            const float2 fq = __half22float2(q4.h[i]);
            const float2 fk = __half22float2(k4.h[i]);
            qf[2 * i] = fq.x; qf[2 * i + 1] = fq.y;
            kf[2 * i] = fk.x; kf[2 * i + 1] = fk.y;
        }

        // h1 partials over this lane's 8 channels
        float part[8];
        #pragma unroll
        for (int jj = 0; jj < 8; ++jj) part[jj] = 0.f;
        #pragma unroll
        for (int i = 0; i < 8; ++i) {
            const float ar = fmaxf(kf[i] - qf[i] + p, 0.f);
            #pragma unroll
            for (int jj = 0; jj < 8; ++jj)
                part[jj] = fmaf(ar, W1reg[i][jj], part[jj]);
        }
        // octet butterfly: every lane gets the full h1 vector
        #pragma unroll
        for (int jj = 0; jj < 8; ++jj) {
            part[jj] += __shfl_xor(part[jj], 1);
            part[jj] += __shfl_xor(part[jj], 2);
            part[jj] += __shfl_xor(part[jj], 4);
        }

        // distributed logit: lane r computes h2[r] only
        float h2 = b2r;
        #pragma unroll
        for (int jj = 0; jj < 8; ++jj) {
            const float h1 = fmaxf(part[jj] + b1u[jj], 0.f);
            h2 = fmaf(h1, W2col[jj], h2);
        }

        // octet softmax
        float mx = h2;
        mx = fmaxf(mx, __shfl_xor(mx, 1));
        mx = fmaxf(mx, __shfl_xor(mx, 2));
        mx = fmaxf(mx, __shfl_xor(mx, 4));
        const float ex = __expf(h2 - mx);
        float s = ex;
        s += __shfl_xor(s, 1);
        s += __shfl_xor(s, 2);
        s += __shfl_xor(s, 4);
        const float w = ex / s;

        // coalesced outputs
        wout[(size_t)e * 8 + r] = __half_as_ushort(__float2half_rn(w));
        if (r == 0) pf[e] = p;
        if (r == 1) atomicAdd(&cnt[sd.x], 1);
    }
}

// ---------------------------------------------------------------------------
// Hierarchical scan, step A: per-1024-element block sums (49 blocks).
// ---------------------------------------------------------------------------
__global__ __launch_bounds__(256) void scan_sums(
    const int* __restrict__ cnt, int* __restrict__ bsum)
{
    const int tid  = threadIdx.x;
    const int base = blockIdx.x * SCAN_TILE + tid * 4;
    int s = 0;
    if (base + 3 < N_NODES) {
        const int4 t = *reinterpret_cast<const int4*>(&cnt[base]);
        s = t.x + t.y + t.z + t.w;
    } else {
        #pragma unroll
        for (int i = 0; i < 4; ++i)
            if (base + i < N_NODES) s += cnt[base + i];
    }
    #pragma unroll
    for (int d = 1; d < 64; d <<= 1) s += __shfl_xor(s, d);
    __shared__ int ws[4];
    if ((tid & 63) == 0) ws[tid >> 6] = s;
    __syncthreads();
    if (tid == 0) bsum[blockIdx.x] = ws[0] + ws[1] + ws[2] + ws[3];
}

// ---------------------------------------------------------------------------
// Hierarchical scan, step B: exclusive scan of the 49 block sums (one wave).
// ---------------------------------------------------------------------------
__global__ __launch_bounds__(64) void scan_bsum(int* __restrict__ bsum)
{
    const int lane = threadIdx.x;
    const int v = (lane < SCAN_NBLK) ? bsum[lane] : 0;
    int incl = v;
    #pragma unroll
    for (int d = 1; d < 64; d <<= 1) {
        const int t = __shfl_up(incl, d);
        if (lane >= d) incl += t;
    }
    if (lane < SCAN_NBLK) bsum[lane] = incl - v;
}

// ---------------------------------------------------------------------------
// Hierarchical scan, step C: local exclusive scan + block offset.
// Writes off[] and re-purposes cnt[] (in-place) as the scatter cursor.
// ---------------------------------------------------------------------------
__global__ __launch_bounds__(256) void scan_final(
    int* __restrict__ cnt, const int* __restrict__ bsum, int* __restrict__ off)
{
    const int tid  = threadIdx.x;
    const int base = blockIdx.x * SCAN_TILE + tid * 4;

    int v0 = 0, v1 = 0, v2 = 0, v3 = 0;
    if (base + 3 < N_NODES) {
        const int4 t = *reinterpret_cast<const int4*>(&cnt[base]);
        v0 = t.x; v1 = t.y; v2 = t.z; v3 = t.w;
    } else {
        if (base + 0 < N_NODES) v0 = cnt[base + 0];
        if (base + 1 < N_NODES) v1 = cnt[base + 1];
        if (base + 2 < N_NODES) v2 = cnt[base + 2];
        if (base + 3 < N_NODES) v3 = cnt[base + 3];
    }
    const int s = v0 + v1 + v2 + v3;

    int incl = s;
    #pragma unroll
    for (int d = 1; d < 64; d <<= 1) {
        const int t = __shfl_up(incl, d);
        if ((tid & 63) >= d) incl += t;
    }
    __shared__ int wsum[4];
    const int wave = tid >> 6;
    if ((tid & 63) == 63) wsum[wave] = incl;
    __syncthreads();
    int woff = 0;
    #pragma unroll
    for (int w = 0; w < 3; ++w)
        if (w < wave) woff += wsum[w];

    int run = bsum[blockIdx.x] + woff + (incl - s);
    if (base + 0 < N_NODES) { off[base + 0] = run; cnt[base + 0] = run; run += v0; }
    if (base + 1 < N_NODES) { off[base + 1] = run; cnt[base + 1] = run; run += v1; }
    if (base + 2 < N_NODES) { off[base + 2] = run; cnt[base + 2] = run; run += v2; }
    if (base + 3 < N_NODES) { off[base + 3] = run; cnt[base + 3] = run; run += v3; }

    if (blockIdx.x == 0 && tid == 0) off[N_NODES] = E_EDGES;
}

// ---------------------------------------------------------------------------
// Scatter: move precomputed {p,dst} + 16B weight record into CSR order.
// ---------------------------------------------------------------------------
__global__ __launch_bounds__(256) void scatter_kernel(
    const int* __restrict__ eidx, const float* __restrict__ pf,
    const uint4* __restrict__ warr,
    int* __restrict__ cursor, float2* __restrict__ ep2, uint4* __restrict__ wcsr)
{
    const int e = blockIdx.x * 256 + threadIdx.x;
    const int2 sd = *reinterpret_cast<const int2*>(&eidx[2 * e]);
    const float p = pf[e];
    const uint4 w8 = warr[e];

    const int pos = atomicAdd(&cursor[sd.x], 1);
    ep2[pos]  = make_float2(p, __int_as_float(sd.y));
    wcsr[pos] = w8;
}

// ---------------------------------------------------------------------------
// Node accumulation: 16 lanes per node (2 sub-octets split the edge list,
// stride 2). Lane r of each sub-octet owns channels 8r..8r+7. Pure
// gather-FMA: stream ep2/wcsr (broadcast), gather xv row, accumulate.
// Final cross-sub-octet merge: one shfl_xor(8) per channel.
// Grid: 3125 blocks x 16 nodes = 50000 exactly.
// ---------------------------------------------------------------------------
__global__ __launch_bounds__(256) void node_accum(
    const int* __restrict__ off, const float2* __restrict__ ep2,
    const uint4* __restrict__ wcsr, const __half* __restrict__ xv,
    float* __restrict__ out)
{
    const int tid  = threadIdx.x;
    const int lane = tid & 63;
    const int grp  = lane >> 4;        // 4 node-groups per wave
    const int sub  = (lane >> 3) & 1;  // sub-octet within group
    const int r    = lane & 7;         // channel block
    const int wave = tid >> 6;

    const int node = blockIdx.x * 16 + wave * 4 + grp;   // always < 50000

    const int beg = off[node];
    const int end = off[node + 1];

    float acc[8];
    #pragma unroll
    for (int i = 0; i < 8; ++i) acc[i] = 0.f;

    int j = beg + sub;
    float2 ep;
    uint4  w8;
    if (j < end) { ep = ep2[j]; w8 = wcsr[j]; }

    for (; j < end; j += 2) {
        const float p   = ep.x;
        const int   dst = __float_as_int(ep.y);

        union { uint4 u; __half2 h[4]; } v4, wz;
        v4.u = *reinterpret_cast<const uint4*>(&xv[(size_t)dst * 64 + 8 * r]);
        wz.u = w8;

        // prefetch next record
        if (j + 2 < end) { ep = ep2[j + 2]; w8 = wcsr[j + 2]; }

        #pragma unroll
        for (int i = 0; i < 4; ++i) {
            const float2 fv = __half22float2(v4.h[i]);
            const float2 fw = __half22float2(wz.h[i]);
            acc[2 * i]     = fmaf(fv.x + p, fw.x, acc[2 * i]);
            acc[2 * i + 1] = fmaf(fv.y + p, fw.y, acc[2 * i + 1]);
        }
    }

    // merge the two sub-octets
    #pragma unroll
    for (int i = 0; i < 8; ++i)
        acc[i] += __shfl_xor(acc[i], 8);

    if (sub == 0) {
        float* orow = &out[(size_t)node * 64 + 8 * r];
        *reinterpret_cast<float4*>(orow)     = make_float4(acc[0], acc[1], acc[2], acc[3]);
        *reinterpret_cast<float4*>(orow + 4) = make_float4(acc[4], acc[5], acc[6], acc[7]);
    }
}

extern "C" void kernel_launch(void* const* d_in, const int* in_sizes, int n_in,
                              void* d_out, int out_size, void* d_ws, size_t ws_size,
                              hipStream_t stream) {
    const float* q     = (const float*)d_in[0];
    const float* k     = (const float*)d_in[1];
    const float* v     = (const float*)d_in[2];
    const float* edges = (const float*)d_in[3];
    const int*   eidx  = (const int*)d_in[4];
    const float* Wq    = (const float*)d_in[5];
    const float* bq    = (const float*)d_in[6];
    const float* Wk    = (const float*)d_in[7];
    const float* bk    = (const float*)d_in[8];
    const float* Wv    = (const float*)d_in[9];
    const float* bv    = (const float*)d_in[10];
    const float* Wp    = (const float*)d_in[11];
    const float* bp    = (const float*)d_in[12];
    const float* W1    = (const float*)d_in[13];
    const float* b1    = (const float*)d_in[14];
    const float* W2    = (const float*)d_in[15];
    const float* b2    = (const float*)d_in[16];
    float* out = (float*)d_out;

    // workspace layout
    char* ws = (char*)d_ws;
    __half* xq = (__half*)ws;          ws += (size_t)N_NODES * 64 * sizeof(__half);
    __half* xk = (__half*)ws;          ws += (size_t)N_NODES * 64 * sizeof(__half);
    __half* xv = (__half*)ws;          ws += (size_t)N_NODES * 64 * sizeof(__half);
    int* cnt  = (int*)ws;              ws += (size_t)(N_NODES + 64) * sizeof(int);
    int* off  = (int*)ws;              ws += (size_t)(N_NODES + 64) * sizeof(int);
    int* bsum = (int*)ws;              ws += (size_t)64 * sizeof(int);
    ushort* wout = (ushort*)ws;        ws += (size_t)E_EDGES * 8 * sizeof(ushort);   // 12.8 MB
    float*  pf   = (float*)ws;         ws += (size_t)E_EDGES * sizeof(float);        // 3.2 MB
    float2* ep2  = (float2*)ws;        ws += (size_t)E_EDGES * sizeof(float2);       // 6.4 MB
    uint4*  wcsr = (uint4*)ws;         ws += (size_t)E_EDGES * sizeof(uint4);        // 12.8 MB

    hipMemsetAsync(cnt, 0, (size_t)N_NODES * sizeof(int), stream);

    proj_kernel<<<dim3((N_NODES + 63) / 64), dim3(256), 0, stream>>>(
        q, k, v, Wq, bq, Wk, bk, Wv, bv, xq, xk, xv);

    edge_weights<<<dim3(E_EDGES / (32 * EW_EPT)), dim3(256), 0, stream>>>(
        eidx, edges, Wp, bp, W1, b1, W2, b2, xq, xk, wout, pf, cnt);

    scan_sums<<<dim3(SCAN_NBLK), dim3(256), 0, stream>>>(cnt, bsum);
    scan_bsum<<<dim3(1), dim3(64), 0, stream>>>(bsum);
    scan_final<<<dim3(SCAN_NBLK), dim3(256), 0, stream>>>(cnt, bsum, off);

    scatter_kernel<<<dim3(E_EDGES / 256), dim3(256), 0, stream>>>(
        eidx, pf, (const uint4*)wout, cnt, ep2, wcsr);

    node_accum<<<dim3(N_NODES / 16), dim3(256), 0, stream>>>(
        off, ep2, wcsr, xv, out);
}